// Round 10
// baseline (199.213 us; speedup 1.0000x reference)
//
#include <hip/hip_runtime.h>
#include <hip/hip_bf16.h>

// Sparse encoder layer: 3x submanifold conv (27-pt) + strided conv (8-pt),
// 4x training-mode BN+ReLU. bf16 MFMA (fp32 accum) for all convs.
//
// R9 finding: conv time invariant under bytes/lines/MLP/occupancy/L2-affinity
// -> limiter is divergent-address processing (~1 lane-addr/cy/CU; 14.7M
// lane-addrs/conv = ~24us floor). R10: per-block dedup'd halo. ~896 rulebook
// entries/block dedup to ~150 unique rows (perm-space locality); k_halo
// builds haloList + byte-local rulebook once (serves all 3 convs); conv
// stages unique rows to LDS (6x fewer divergent addrs) and ds_reads A-frags.
// BN+ReLU re-fused at stage time (once per row; row N == zero row fixes the
// R4 mask bug structurally). Overflow (>255 unique) -> exact global fallback.
//
// ws layout (bytes):
//   [0, 32768)      : stats partials, 4 stages x NCOPY(32) x 64 floats
//   [32768, 221184) : w1t/w2at/w2bt bf16 [28][32][32] + w3t [8][32][32]
//   [221184, +3x(N+1)*64) : X, T, FB bf16 [N+1,32], row N = 0 (perm space)
//   then: perm[N], invperm[N], nbrT[28][N], childT[8][MP], blockCnt[256],
//         haloList[NB*256] int, cntG[NB] int, nbrL[NB*896] u8

typedef __bf16 bf16_8 __attribute__((ext_vector_type(8)));
typedef float  f32x4  __attribute__((ext_vector_type(4)));

#define EPSV 1e-5f
#define NCOPY 32
#define CBLK 256
#define HMAX 255   // halo capacity (255 = u8 sentinel-compatible)
#define HST 40     // bf16 elems per halo row in LDS (80 B stride, bank spread)

__device__ inline bf16_8 bzero8() {
    bf16_8 z;
#pragma unroll
    for (int i = 0; i < 8; ++i) z[i] = (__bf16)0.f;
    return z;
}

// ---- stage 1: count valid child slots per chunk ----
__global__ __launch_bounds__(256) void k_cnt(const int* __restrict__ child, int m8,
                                             int* __restrict__ blockCnt) {
    __shared__ int ws[4];
    const int b = blockIdx.x, tid = threadIdx.x;
    const int chunk = (m8 + CBLK - 1) / CBLK;
    const int s0 = b * chunk, s1 = min(s0 + chunk, m8);
    int c = 0;
    for (int s = s0 + tid; s < s1; s += 256) c += (child[s] >= 0);
#pragma unroll
    for (int d = 1; d < 64; d <<= 1) c += __shfl_xor(c, d);
    if ((tid & 63) == 0) ws[tid >> 6] = c;
    __syncthreads();
    if (tid == 0) blockCnt[b] = ws[0] + ws[1] + ws[2] + ws[3];
}

// ---- stage 2: order-preserving compaction -> perm, invperm ----
__global__ __launch_bounds__(256) void k_compact(const int* __restrict__ child, int m8,
                                                 const int* __restrict__ blockCnt,
                                                 int* __restrict__ perm,
                                                 int* __restrict__ invperm) {
    __shared__ int woff[4];
    __shared__ int sbase;
    const int b = blockIdx.x, tid = threadIdx.x;
    const int chunk = (m8 + CBLK - 1) / CBLK;
    const int s0 = b * chunk, s1 = min(s0 + chunk, m8);
    if (tid == 0) {
        int a = 0;
        for (int i = 0; i < b; ++i) a += blockCnt[i];
        sbase = a;
    }
    __syncthreads();
    int off = sbase;
    for (int base = s0; base < s1; base += 256) {
        const int s = base + tid;
        int c = -1;
        bool v = false;
        if (s < s1) { c = child[s]; v = (c >= 0); }
        unsigned long long m = __ballot(v);
        if ((tid & 63) == 0) woff[tid >> 6] = __popcll(m);
        __syncthreads();
        const int wv = tid >> 6;
        int wpre = 0;
#pragma unroll
        for (int i = 0; i < 4; ++i) if (i < wv) wpre += woff[i];
        const int tot = woff[0] + woff[1] + woff[2] + woff[3];
        const int rank = __popcll(m & ((1ULL << (tid & 63)) - 1ULL));
        if (v) {
            const int pos = off + wpre + rank;
            perm[pos] = c;
            invperm[c] = pos;
        }
        off += tot;
        __syncthreads();
    }
}

// ---- stage 3: k-major rulebooks (ZR-padded) + permuted features + weights ----
__global__ __launch_bounds__(256) void k_reindex(
    const int* __restrict__ nbr, const int* __restrict__ child,
    const int* __restrict__ perm, const int* __restrict__ invperm,
    const float* __restrict__ feats,
    const float* __restrict__ W1, const float* __restrict__ W2a,
    const float* __restrict__ W2b, const float* __restrict__ W3,
    int* __restrict__ nbrT, int* __restrict__ childT,
    __bf16* __restrict__ X, __bf16* __restrict__ T, __bf16* __restrict__ FB,
    __bf16* __restrict__ w1t, __bf16* __restrict__ w2at,
    __bf16* __restrict__ w2bt, __bf16* __restrict__ w3t,
    float* __restrict__ statsAll,
    int N, int M, int MP) {
    int t = blockIdx.x * 256 + threadIdx.x;
    if (t < 28 * N) {  // nbrT [28][N], k==27 -> ZR(=N)
        const int k = t / N, p = t - k * N;
        int o = N;
        if (k < 27) {
            const int v = nbr[(size_t)perm[p] * 27 + k];
            o = (v < 0) ? N : invperm[v];
        }
        nbrT[t] = o;
        return;
    }
    t -= 28 * N;
    if (t < 8 * MP) {  // childT [8][MP], m >= M -> ZR
        const int k = t / MP, m = t - k * MP;
        int o = N;
        if (m < M) {
            const int v = child[(size_t)m * 8 + k];
            o = (v < 0) ? N : invperm[v];
        }
        childT[t] = o;
        return;
    }
    t -= 8 * MP;
    if (t < N * 32) {  // permuted features
        const int p = t >> 5, c = t & 31;
        FB[t] = (c < 3) ? (__bf16)feats[(size_t)perm[p] * 3 + c] : (__bf16)0.f;
        return;
    }
    t -= N * 32;
    if (t < 96) {  // zero row N of X, T, FB
        const int b = t >> 5, c = t & 31;
        __bf16* p = (b == 0) ? X : (b == 1) ? T : FB;
        p[(size_t)N * 32 + c] = (__bf16)0.f;
        return;
    }
    t -= 96;
    if (t < 28672) {
        const int k = t >> 10, r = t & 1023, d = r >> 5, c = r & 31;
        w1t[t] = (k < 27 && c < 3) ? (__bf16)W1[(k * 3 + c) * 32 + d] : (__bf16)0.f;
        return;
    }
    t -= 28672;
    if (t < 28672) {
        const int k = t >> 10, r = t & 1023, d = r >> 5, c = r & 31;
        w2at[t] = (k < 27) ? (__bf16)W2a[(k * 32 + c) * 32 + d] : (__bf16)0.f;
        return;
    }
    t -= 28672;
    if (t < 28672) {
        const int k = t >> 10, r = t & 1023, d = r >> 5, c = r & 31;
        w2bt[t] = (k < 27) ? (__bf16)W2b[(k * 32 + c) * 32 + d] : (__bf16)0.f;
        return;
    }
    t -= 28672;
    if (t < 8192) {
        const int k = t >> 10, r = t & 1023, d = r >> 5, c = r & 31;
        w3t[t] = (__bf16)W3[(k * 32 + c) * 32 + d];
        return;
    }
    t -= 8192;
    if (t < 4 * NCOPY * 64) statsAll[t] = 0.f;
}

// ---- stage 4: per-block halo dedup (runs once, serves all three 27-pt convs)
// Block b covers perm sites [b*32, b*32+32). Hash-dedup the 28x32 rulebook
// entries; haloList[b][l] = global row of local slot l (< HMAX);
// nbrL[b][k][s] = local slot (255 = overflow -> conv does global fallback).
__global__ __launch_bounds__(256) void k_halo(
    const int* __restrict__ nbrT, int N,
    int* __restrict__ haloList, unsigned char* __restrict__ nbrL,
    int* __restrict__ cntG) {
    __shared__ int key[1024];
    __shared__ int loc[1024];
    __shared__ int hcnt;
    const int b = blockIdx.x, tid = threadIdx.x;
    const int base = b * 32;
    for (int i = tid; i < 1024; i += 256) key[i] = -1;
    if (tid == 0) hcnt = 0;
    __syncthreads();
    // pass 1: insert
    for (int e = tid; e < 896; e += 256) {
        const int k = e >> 5, s = e & 31;
        const int nb = nbrT[(size_t)k * N + base + s];
        unsigned h = ((unsigned)nb * 2654435761u) >> 22;
        while (true) {
            int old = atomicCAS(&key[h], -1, nb);
            if (old == -1 || old == nb) break;
            h = (h + 1) & 1023;
        }
    }
    __syncthreads();
    // pass 2: compact -> local slots
    for (int i = tid; i < 1024; i += 256) {
        if (key[i] != -1) {
            const int l = atomicAdd(&hcnt, 1);
            if (l < HMAX) {
                loc[i] = l;
                haloList[(size_t)b * 256 + l] = key[i];
            } else {
                loc[i] = HMAX;  // overflow sentinel
            }
        }
    }
    __syncthreads();
    // pass 3: emit byte rulebook
    for (int e = tid; e < 896; e += 256) {
        const int k = e >> 5, s = e & 31;
        const int nb = nbrT[(size_t)k * N + base + s];
        unsigned h = ((unsigned)nb * 2654435761u) >> 22;
        while (key[h] != nb) h = (h + 1) & 1023;
        nbrL[(size_t)b * 896 + e] = (unsigned char)loc[h];
    }
    if (tid == 0) cntG[b] = min(hcnt, HMAX);
}

// Halo-staged 27-pt conv. Block = 4 waves, 32 sites; wave w owns offsets
// [7w, 7w+7). Stage cnt unique rows to LDS (optional fused BN+ReLU: applied
// once per row; row N -> zero AFTER BN = reference mask semantics), then
// A-frags via ds_read_b128. Local idx 255 -> exact global fallback.
template <bool ADD, bool BNST>
__global__ __launch_bounds__(256, 4) void k_convh(
    const __bf16* __restrict__ src,       // [N+1,32] bf16 raw (pre-BN)
    const int* __restrict__ nbrT,         // [28][N] (fallback path)
    const unsigned char* __restrict__ nbrL,
    const int* __restrict__ haloList, const int* __restrict__ cntG,
    const __bf16* __restrict__ Wt,        // [28][32][32]
    const __bf16* __restrict__ addsrc,    // raw x1 or null
    __bf16* __restrict__ dst,             // [N,32] raw conv output
    const float* __restrict__ spart_in,   // producer stats partials (BNST)
    const float* __restrict__ gamma, const float* __restrict__ beta,
    float inv_cnt_in,
    float* __restrict__ spart_out, int N) {
    __shared__ __bf16 halo[HMAX * HST];   // 20.4 KB
    __shared__ float part[4][32][34];
    __shared__ float lst[64];
    __shared__ float sfin[64];
    __shared__ float lsc[32], lsh[32];

    const int tid = threadIdx.x;
    const int lane = tid & 63;
    const int wv = tid >> 6;
    const int b = blockIdx.x;
    const int base = b * 32;
    const int sl = lane & 15;
    const int kh = lane >> 4;
    const int kbeg = wv * 7;

    if (tid < 64) lst[tid] = 0.f;

    if (BNST) {
        if (tid < 64) {
            float a = 0.f;
#pragma unroll
            for (int i = 0; i < NCOPY; ++i) a += spart_in[i * 64 + tid];
            sfin[tid] = a;
        }
        __syncthreads();
        if (tid < 32) {
            float mu = sfin[tid] * inv_cnt_in;
            float var = sfin[32 + tid] * inv_cnt_in - mu * mu;
            float s = gamma[tid] * rsqrtf(var + EPSV);
            lsc[tid] = s;
            lsh[tid] = beta[tid] - mu * s;
        }
    }
    __syncthreads();  // lst + (lsc/lsh) visible

    // ---- stage halo rows (cnt*4 16B chunks, fused BN once per row) ----
    const int cnt = cntG[b];
    for (int i = tid; i < cnt * 4; i += 256) {
        const int slot = i >> 2, q = i & 3;
        const int row = haloList[(size_t)b * 256 + slot];
        bf16_8 v = *(const bf16_8*)(src + (size_t)row * 32 + q * 8);
        if (BNST) {
            if (row == N) {
                v = bzero8();  // missing neighbor: zero AFTER BN (ref semantics)
            } else {
#pragma unroll
                for (int u = 0; u < 8; ++u)
                    v[u] = (__bf16)fmaxf(fmaf((float)v[u], lsc[q * 8 + u], lsh[q * 8 + u]), 0.f);
            }
        }
        *(bf16_8*)(&halo[slot * HST + q * 8]) = v;
    }
    __syncthreads();

    // ---- local rulebook bytes ----
    unsigned char li[2][7];
#pragma unroll
    for (int j = 0; j < 7; ++j)
#pragma unroll
        for (int g = 0; g < 2; ++g)
            li[g][j] = nbrL[(size_t)b * 896 + (kbeg + j) * 32 + g * 16 + sl];

    // ---- A-frags from LDS ----
    bf16_8 av[2][7];
#pragma unroll
    for (int j = 0; j < 7; ++j)
#pragma unroll
        for (int g = 0; g < 2; ++g) {
            const int la = li[g][j];
            const int ls = (la == HMAX) ? 0 : la;
            av[g][j] = *(const bf16_8*)(&halo[ls * HST + kh * 8]);
        }
    // ---- overflow fallback (exact; ~never taken) ----
#pragma unroll
    for (int j = 0; j < 7; ++j)
#pragma unroll
        for (int g = 0; g < 2; ++g) {
            if (li[g][j] == HMAX) {
                const int row = nbrT[(size_t)(kbeg + j) * N + base + g * 16 + sl];
                bf16_8 v = *(const bf16_8*)(src + (size_t)row * 32 + kh * 8);
                if (BNST) {
                    if (row == N) {
                        v = bzero8();
                    } else {
#pragma unroll
                        for (int u = 0; u < 8; ++u)
                            v[u] = (__bf16)fmaxf(fmaf((float)v[u], lsc[kh * 8 + u], lsh[kh * 8 + u]), 0.f);
                    }
                }
                av[g][j] = v;
            }
        }

    // ---- MFMA chain ----
    f32x4 acc[2][2];
#pragma unroll
    for (int g = 0; g < 2; ++g)
#pragma unroll
        for (int h = 0; h < 2; ++h)
#pragma unroll
            for (int r = 0; r < 4; ++r) acc[g][h][r] = 0.f;

#pragma unroll
    for (int j = 0; j < 7; ++j) {
        const int kk = kbeg + j;
        bf16_8 b0 = *(const bf16_8*)(Wt + kk * 1024 + sl * 32 + kh * 8);
        bf16_8 b1 = *(const bf16_8*)(Wt + kk * 1024 + (16 + sl) * 32 + kh * 8);
        acc[0][0] = __builtin_amdgcn_mfma_f32_16x16x32_bf16(av[0][j], b0, acc[0][0], 0, 0, 0);
        acc[0][1] = __builtin_amdgcn_mfma_f32_16x16x32_bf16(av[0][j], b1, acc[0][1], 0, 0, 0);
        acc[1][0] = __builtin_amdgcn_mfma_f32_16x16x32_bf16(av[1][j], b0, acc[1][0], 0, 0, 0);
        acc[1][1] = __builtin_amdgcn_mfma_f32_16x16x32_bf16(av[1][j], b1, acc[1][1], 0, 0, 0);
    }

    // ---- partials to LDS ----
#pragma unroll
    for (int g = 0; g < 2; ++g)
#pragma unroll
        for (int h = 0; h < 2; ++h)
#pragma unroll
            for (int r = 0; r < 4; ++r)
                part[wv][g * 16 + kh * 4 + r][h * 16 + sl] = acc[g][h][r];
    __syncthreads();

    // ---- reduce + epilogue ----
    if (tid < 128) {
        const int sloc = tid >> 2;
        const int c0 = (tid & 3) * 8;
        float v[8];
#pragma unroll
        for (int i = 0; i < 8; ++i)
            v[i] = part[0][sloc][c0 + i] + part[1][sloc][c0 + i] +
                   part[2][sloc][c0 + i] + part[3][sloc][c0 + i];
        const int site = base + sloc;
        if (ADD) {
            bf16_8 ad = *(const bf16_8*)(addsrc + (size_t)site * 32 + c0);
#pragma unroll
            for (int i = 0; i < 8; ++i) v[i] += (float)ad[i];
        }
        bf16_8 o;
#pragma unroll
        for (int i = 0; i < 8; ++i) o[i] = (__bf16)v[i];
        *(bf16_8*)(dst + (size_t)site * 32 + c0) = o;
        float sv[8], qv[8];
#pragma unroll
        for (int i = 0; i < 8; ++i) { sv[i] = v[i]; qv[i] = v[i] * v[i]; }
#pragma unroll
        for (int d = 4; d < 64; d <<= 1) {
#pragma unroll
            for (int i = 0; i < 8; ++i) {
                sv[i] += __shfl_xor(sv[i], d);
                qv[i] += __shfl_xor(qv[i], d);
            }
        }
        if ((lane & 60) == 0) {
#pragma unroll
            for (int i = 0; i < 8; ++i) {
                atomicAdd(&lst[c0 + i], sv[i]);
                atomicAdd(&lst[32 + c0 + i], qv[i]);
            }
        }
    }
    __syncthreads();
    if (tid < 64)
        atomicAdd(&spart_out[(b & (NCOPY - 1)) * 64 + tid], lst[tid]);
}

// Direct-gather conv (8-pt strided conv3). Unchanged structure from R8.
template <int KOFF, bool ADD>
__global__ __launch_bounds__(256, 4) void k_conv(
    const __bf16* __restrict__ src, const int* __restrict__ idxT,
    const __bf16* __restrict__ Wt, const __bf16* __restrict__ addsrc,
    __bf16* __restrict__ dst, float* __restrict__ spart_out,
    int nout, int npad) {
    constexpr int KPAD = ((KOFF + 3) / 4) * 4;
    constexpr int KPW = KPAD / 4;
    __shared__ float part[4][32][34];
    __shared__ float lst[64];
    const int tid = threadIdx.x;
    const int lane = tid & 63;
    const int wv = tid >> 6;
    const int base = blockIdx.x * 32;
    const int sl = lane & 15;
    const int kh = lane >> 4;
    const int kbeg = wv * KPW;
    if (tid < 64) lst[tid] = 0.f;
    int nb[2][KPW];
#pragma unroll
    for (int j = 0; j < KPW; ++j)
#pragma unroll
        for (int g = 0; g < 2; ++g)
            nb[g][j] = idxT[(kbeg + j) * npad + base + g * 16 + sl];
    bf16_8 av[2][KPW];
#pragma unroll
    for (int j = 0; j < KPW; ++j)
#pragma unroll
        for (int g = 0; g < 2; ++g)
            av[g][j] = *(const bf16_8*)(src + (size_t)nb[g][j] * 32 + kh * 8);
    f32x4 acc[2][2];
#pragma unroll
    for (int g = 0; g < 2; ++g)
#pragma unroll
        for (int h = 0; h < 2; ++h)
#pragma unroll
            for (int r = 0; r < 4; ++r) acc[g][h][r] = 0.f;
#pragma unroll
    for (int j = 0; j < KPW; ++j) {
        const int kk = kbeg + j;
        bf16_8 b0 = *(const bf16_8*)(Wt + kk * 1024 + sl * 32 + kh * 8);
        bf16_8 b1 = *(const bf16_8*)(Wt + kk * 1024 + (16 + sl) * 32 + kh * 8);
        acc[0][0] = __builtin_amdgcn_mfma_f32_16x16x32_bf16(av[0][j], b0, acc[0][0], 0, 0, 0);
        acc[0][1] = __builtin_amdgcn_mfma_f32_16x16x32_bf16(av[0][j], b1, acc[0][1], 0, 0, 0);
        acc[1][0] = __builtin_amdgcn_mfma_f32_16x16x32_bf16(av[1][j], b0, acc[1][0], 0, 0, 0);
        acc[1][1] = __builtin_amdgcn_mfma_f32_16x16x32_bf16(av[1][j], b1, acc[1][1], 0, 0, 0);
    }
#pragma unroll
    for (int g = 0; g < 2; ++g)
#pragma unroll
        for (int h = 0; h < 2; ++h)
#pragma unroll
            for (int r = 0; r < 4; ++r)
                part[wv][g * 16 + kh * 4 + r][h * 16 + sl] = acc[g][h][r];
    __syncthreads();
    if (tid < 128) {
        const int sloc = tid >> 2;
        const int c0 = (tid & 3) * 8;
        float v[8];
#pragma unroll
        for (int i = 0; i < 8; ++i)
            v[i] = part[0][sloc][c0 + i] + part[1][sloc][c0 + i] +
                   part[2][sloc][c0 + i] + part[3][sloc][c0 + i];
        const int site = base + sloc;
        if (site < nout) {
            if (ADD) {
                bf16_8 ad = *(const bf16_8*)(addsrc + (size_t)site * 32 + c0);
#pragma unroll
                for (int i = 0; i < 8; ++i) v[i] += (float)ad[i];
            }
            bf16_8 o;
#pragma unroll
            for (int i = 0; i < 8; ++i) o[i] = (__bf16)v[i];
            *(bf16_8*)(dst + (size_t)site * 32 + c0) = o;
        } else {
#pragma unroll
            for (int i = 0; i < 8; ++i) v[i] = 0.f;
        }
        float sv[8], qv[8];
#pragma unroll
        for (int i = 0; i < 8; ++i) { sv[i] = v[i]; qv[i] = v[i] * v[i]; }
#pragma unroll
        for (int d = 4; d < 64; d <<= 1) {
#pragma unroll
            for (int i = 0; i < 8; ++i) {
                sv[i] += __shfl_xor(sv[i], d);
                qv[i] += __shfl_xor(qv[i], d);
            }
        }
        if ((lane & 60) == 0) {
#pragma unroll
            for (int i = 0; i < 8; ++i) {
                atomicAdd(&lst[c0 + i], sv[i]);
                atomicAdd(&lst[32 + c0 + i], qv[i]);
            }
        }
    }
    __syncthreads();
    if (tid < 64)
        atomicAdd(&spart_out[(blockIdx.x & (NCOPY - 1)) * 64 + tid], lst[tid]);
}

// BN+ReLU apply (stats prolog). bf16 out (perm space) and/or fp32 out
// (scattered via permw).
template <bool WF32, bool WBF>
__global__ __launch_bounds__(256) void k_bn(
    const __bf16* __restrict__ src, const float* __restrict__ spart,
    const float* __restrict__ gamma, const float* __restrict__ beta,
    float inv_cnt, int nrows,
    __bf16* __restrict__ dstb, float* __restrict__ dstf,
    const int* __restrict__ permw) {
    __shared__ float ss[64];
    __shared__ float sc[32], sh[32];
    const int tid = threadIdx.x;
    if (tid < 64) {
        float a = 0.f;
#pragma unroll
        for (int i = 0; i < NCOPY; ++i) a += spart[i * 64 + tid];
        ss[tid] = a;
    }
    __syncthreads();
    if (tid < 32) {
        float mu = ss[tid] * inv_cnt;
        float var = ss[32 + tid] * inv_cnt - mu * mu;
        float s = gamma[tid] * rsqrtf(var + EPSV);
        sc[tid] = s;
        sh[tid] = beta[tid] - mu * s;
    }
    __syncthreads();
    const int gtid = blockIdx.x * blockDim.x + tid;
    const int c0 = (gtid & 3) * 8;
    float scale[8], shift[8];
#pragma unroll
    for (int i = 0; i < 8; ++i) { scale[i] = sc[c0 + i]; shift[i] = sh[c0 + i]; }
    const int rstride = (gridDim.x * blockDim.x) >> 2;
    for (int r = gtid >> 2; r < nrows; r += rstride) {
        const size_t off = (size_t)r * 32 + c0;
        bf16_8 v = *(const bf16_8*)(src + off);
        float y[8];
#pragma unroll
        for (int i = 0; i < 8; ++i) y[i] = fmaxf(fmaf((float)v[i], scale[i], shift[i]), 0.f);
        if (WBF) {
            bf16_8 o;
#pragma unroll
            for (int i = 0; i < 8; ++i) o[i] = (__bf16)y[i];
            *(bf16_8*)(dstb + off) = o;
        }
        if (WF32) {
            f32x4 lo, hi;
#pragma unroll
            for (int i = 0; i < 4; ++i) { lo[i] = y[i]; hi[i] = y[4 + i]; }
            const size_t woff = permw ? ((size_t)permw[r] * 32 + c0) : off;
            *(f32x4*)(dstf + woff) = lo;
            *(f32x4*)(dstf + woff + 4) = hi;
        }
    }
}

extern "C" void kernel_launch(void* const* d_in, const int* in_sizes, int n_in,
                              void* d_out, int out_size, void* d_ws, size_t ws_size,
                              hipStream_t stream) {
    const float* feats = (const float*)d_in[0];
    const int* nbr     = (const int*)d_in[1];
    const int* child   = (const int*)d_in[2];
    const float* W1  = (const float*)d_in[3];
    const float* W2a = (const float*)d_in[4];
    const float* W2b = (const float*)d_in[5];
    const float* W3  = (const float*)d_in[6];
    const float* g1 = (const float*)d_in[7];  const float* b1 = (const float*)d_in[8];
    const float* g2 = (const float*)d_in[9];  const float* b2 = (const float*)d_in[10];
    const float* g3 = (const float*)d_in[11]; const float* b3 = (const float*)d_in[12];
    const float* g4 = (const float*)d_in[13]; const float* b4 = (const float*)d_in[14];

    const int N = in_sizes[0] / 3;        // 131072 (multiple of 32)
    const int M8 = in_sizes[2];
    const int M = M8 / 8;
    const int MP = ((M + 31) / 32) * 32;
    const int NB = N / 32;                // 4096 conv blocks

    float* outp = (float*)d_out;               // [M,32] original order
    float* ft2p = outp + (size_t)M * 32;       // [N,32] original order

    char* ws = (char*)d_ws;
    float* statsAll = (float*)ws;
    __bf16* w1t  = (__bf16*)(ws + 32768);
    __bf16* w2at = w1t + 28672;
    __bf16* w2bt = w2at + 28672;
    __bf16* w3t  = w2bt + 28672;
    __bf16* X  = (__bf16*)(ws + 221184);
    __bf16* T  = X + (size_t)(N + 1) * 32;
    __bf16* FB = T + (size_t)(N + 1) * 32;
    char* p2 = (char*)(FB + (size_t)(N + 1) * 32);
    int* perm    = (int*)p2;
    int* invperm = perm + N;
    int* nbrT    = invperm + N;                           // [28][N]
    int* childT  = nbrT + (size_t)28 * N;                 // [8][MP]
    int* blockCnt = childT + (size_t)8 * MP;
    int* haloList = blockCnt + 256;                       // [NB][256]
    int* cntG     = haloList + (size_t)NB * 256;          // [NB]
    unsigned char* nbrL = (unsigned char*)(cntG + NB);    // [NB][896]

    float* s1 = statsAll;
    float* s2 = statsAll + NCOPY * 64;
    float* s3 = statsAll + 2 * NCOPY * 64;
    float* s4 = statsAll + 3 * NCOPY * 64;

    k_cnt<<<CBLK, 256, 0, stream>>>(child, M8, blockCnt);
    k_compact<<<CBLK, 256, 0, stream>>>(child, M8, blockCnt, perm, invperm);

    const int rtot = 28 * N + 8 * MP + N * 32 + 96 + 3 * 28672 + 8192 + 4 * NCOPY * 64;
    k_reindex<<<(rtot + 255) / 256, 256, 0, stream>>>(
        nbr, child, perm, invperm, feats, W1, W2a, W2b, W3,
        nbrT, childT, X, T, FB, w1t, w2at, w2bt, w3t, statsAll, N, M, MP);

    k_halo<<<NB, 256, 0, stream>>>(nbrT, N, haloList, nbrL, cntG);

    const float invN = 1.f / N, invM = 1.f / M;

    // x1 = conv1(featsb)                              FB -> X, s1
    k_convh<false, false><<<NB, 256, 0, stream>>>(
        FB, nbrT, nbrL, haloList, cntG, w1t, nullptr, X,
        nullptr, nullptr, nullptr, 0.f, s1, N);
    // br1 = conv2a(bnrelu1(x1)) [BN fused at stage]    X -> T, s2
    k_convh<false, true><<<NB, 256, 0, stream>>>(
        X, nbrT, nbrL, haloList, cntG, w2at, nullptr, T,
        s1, g1, b1, invN, s2, N);
    // s = x1 + conv2b(bnrelu2(br1)) [BN fused]         T (+X) -> FB, s3
    k_convh<true, true><<<NB, 256, 0, stream>>>(
        T, nbrT, nbrL, haloList, cntG, w2bt, X, FB,
        s2, g2, b2, invN, s3, N);
    // ft2 = bnrelu3(s)                                 FB -> T (bf16) + ft2p (fp32 scatter)
    k_bn<true, true><<<1024, 256, 0, stream>>>(FB, s3, g3, b3, invN, N, T, ft2p, perm);
    // x3 = conv3(ft2)                                  T -> X rows [0,M), s4
    k_conv<8, false><<<MP / 32, 256, 0, stream>>>(T, childT, w3t, nullptr, X, s4, M, MP);
    // out = bnrelu4(x3)                                X -> outp
    k_bn<true, false><<<1024, 256, 0, stream>>>(X, s4, g4, b4, invM, M, nullptr, outp, nullptr);
}

// Round 11
// 176.833 us; speedup vs baseline: 1.1266x; 1.1266x over previous
//
#include <hip/hip_runtime.h>
#include <hip/hip_bf16.h>

// Sparse encoder layer: 3x submanifold conv (27-pt) + strided conv (8-pt),
// 4x training-mode BN+ReLU. bf16 MFMA (fp32 accum) for all convs.
//
// R10 finding: gather wall (~38-43us/conv) invariant under bytes/lines/MLP/
// occupancy/L2-affinity/address-count. Stop chasing it; cut self-inflicted
// overhead instead. R11: drop perm machinery entirely (k_compact serial scan
// + 3.5M divergent reindex gathers cost ~25-30us for ~3us/conv benefit);
// original order everywhere; k-major ZR tables via tiled streaming transpose;
// conv simplified: wave owns 16 sites x full K, 8 acc VGPRs, no split-K LDS
// reduce, direct parallel epilogue, (256,4) for deep gather pipelining.
//
// ws layout (bytes):
//   [0, 32768)        : stats partials, 4 stages x NCOPY(32) x 64 floats
//   [32768, 215040)   : w1t/w2at/w2bt bf16 [27][32][32] + w3t [8][32][32]
//   [215040, +3x(N+1)*64) : X, T, FB bf16 [N+1,32], row N = 0
//   then: nbrT[27][N] int, childT[8][MP64] int

typedef __bf16 bf16_8 __attribute__((ext_vector_type(8)));
typedef float  f32x4  __attribute__((ext_vector_type(4)));

#define EPSV 1e-5f
#define NCOPY 32

// ---- prep: padded features, zero rows, weights transpose, stats zero ----
__global__ __launch_bounds__(256) void k_prep(
    const float* __restrict__ feats,
    const float* __restrict__ W1, const float* __restrict__ W2a,
    const float* __restrict__ W2b, const float* __restrict__ W3,
    __bf16* __restrict__ FB, __bf16* __restrict__ X, __bf16* __restrict__ T,
    __bf16* __restrict__ w1t, __bf16* __restrict__ w2at,
    __bf16* __restrict__ w2bt, __bf16* __restrict__ w3t,
    float* __restrict__ statsAll, int N) {
    int t = blockIdx.x * 256 + threadIdx.x;
    const int n32 = N * 32;
    if (t < n32) {  // feats fp32 [N,3] -> bf16 [N,32] zero-padded
        const int s = t >> 5, c = t & 31;
        FB[t] = (c < 3) ? (__bf16)feats[(size_t)s * 3 + c] : (__bf16)0.f;
        return;
    }
    t -= n32;
    if (t < 96) {  // zero row N of X, T, FB
        const int b = t >> 5, c = t & 31;
        __bf16* p = (b == 0) ? X : (b == 1) ? T : FB;
        p[(size_t)N * 32 + c] = (__bf16)0.f;
        return;
    }
    t -= 96;
    if (t < 27648) {  // [27][32d][32c], c>=3 zero
        const int k = t >> 10, r = t & 1023, d = r >> 5, c = r & 31;
        w1t[t] = (c < 3) ? (__bf16)W1[(k * 3 + c) * 32 + d] : (__bf16)0.f;
        return;
    }
    t -= 27648;
    if (t < 27648) {
        const int k = t >> 10, r = t & 1023, d = r >> 5, c = r & 31;
        w2at[t] = (__bf16)W2a[(k * 32 + c) * 32 + d];
        return;
    }
    t -= 27648;
    if (t < 27648) {
        const int k = t >> 10, r = t & 1023, d = r >> 5, c = r & 31;
        w2bt[t] = (__bf16)W2b[(k * 32 + c) * 32 + d];
        return;
    }
    t -= 27648;
    if (t < 8192) {
        const int k = t >> 10, r = t & 1023, d = r >> 5, c = r & 31;
        w3t[t] = (__bf16)W3[(k * 32 + c) * 32 + d];
        return;
    }
    t -= 8192;
    if (t < 4 * NCOPY * 64) statsAll[t] = 0.f;
}

// ---- tiled transpose: nbr [N][27] -> nbrT [27][N], -1 -> N (zero row) ----
__global__ __launch_bounds__(256) void k_tr(const int* __restrict__ nbr,
                                            int* __restrict__ nbrT, int N) {
    const int s = blockIdx.x * 64 + (threadIdx.x & 63);
    const int kq = threadIdx.x >> 6;
#pragma unroll
    for (int it = 0; it < 7; ++it) {
        const int k = kq * 7 + it;
        if (k < 27) {
            const int v = nbr[(size_t)s * 27 + k];
            nbrT[(size_t)k * N + s] = (v < 0) ? N : v;
        }
    }
}

// ---- child [M][8] -> childT [8][MP64], -1 / pad -> N ----
__global__ __launch_bounds__(256) void k_tr3(const int* __restrict__ child,
                                             int* __restrict__ childT,
                                             int M, int MP64, int N) {
    const int m = blockIdx.x * 64 + (threadIdx.x & 63);
    const int kq = threadIdx.x >> 6;
#pragma unroll
    for (int it = 0; it < 2; ++it) {
        const int k = kq * 2 + it;
        const int v = (m < M) ? child[(size_t)m * 8 + k] : -1;
        childT[(size_t)k * MP64 + m] = (v < 0) ? N : v;
    }
}

// Gathered-GEMM conv: block = 4 waves x 16 sites, each wave runs the FULL
// K loop for its 16 sites (8 acc VGPRs, no split-K reduce). Gathers are
// unconditional (ZR row N is zero). Direct parallel epilogue + stats.
template <int KOFF, bool ADD>
__global__ __launch_bounds__(256, 4) void k_conv(
    const __bf16* __restrict__ src,     // [N+1,32] bf16, row N = 0
    const int* __restrict__ idxT,       // [KOFF][npad]
    const __bf16* __restrict__ Wt,      // [KOFF][32d][32c]
    const __bf16* __restrict__ addsrc,  // [nout,32] bf16 or null
    __bf16* __restrict__ dst,           // [nout,32] bf16
    float* __restrict__ spart,          // [NCOPY][64]
    int nout, int npad) {
    __shared__ float lst[64];
    const int tid = threadIdx.x;
    const int lane = tid & 63;
    const int wv = tid >> 6;
    const int sl = lane & 15;   // A row / C col within 16
    const int kh = lane >> 4;   // channel quarter kh*8..kh*8+7
    const int gbase = blockIdx.x * 64 + wv * 16;
    const int s = gbase + sl;

    if (tid < 64) lst[tid] = 0.f;
    __syncthreads();

    f32x4 acc0, acc1;
#pragma unroll
    for (int r = 0; r < 4; ++r) { acc0[r] = 0.f; acc1[r] = 0.f; }

#pragma unroll
    for (int k = 0; k < KOFF; ++k) {
        const int nb = idxT[(size_t)k * npad + s];
        bf16_8 a  = *(const bf16_8*)(src + (size_t)nb * 32 + kh * 8);
        bf16_8 b0 = *(const bf16_8*)(Wt + k * 1024 + sl * 32 + kh * 8);
        bf16_8 b1 = *(const bf16_8*)(Wt + k * 1024 + (16 + sl) * 32 + kh * 8);
        acc0 = __builtin_amdgcn_mfma_f32_16x16x32_bf16(a, b0, acc0, 0, 0, 0);
        acc1 = __builtin_amdgcn_mfma_f32_16x16x32_bf16(a, b1, acc1, 0, 0, 0);
    }

    // ---- epilogue: lane covers C rows kh*4..+3, cols sl and 16+sl ----
    float s0 = 0.f, q0 = 0.f, s1 = 0.f, q1 = 0.f;
#pragma unroll
    for (int r = 0; r < 4; ++r) {
        const int site = gbase + kh * 4 + r;
        if (site < nout) {
            const size_t o0 = (size_t)site * 32 + sl;
            float v0 = acc0[r];
            float v1 = acc1[r];
            if (ADD) {
                v0 += (float)addsrc[o0];
                v1 += (float)addsrc[o0 + 16];
            }
            dst[o0] = (__bf16)v0;
            dst[o0 + 16] = (__bf16)v1;
            s0 += v0; q0 += v0 * v0;
            s1 += v1; q1 += v1 * v1;
        }
    }
    s0 += __shfl_xor(s0, 16); s0 += __shfl_xor(s0, 32);
    q0 += __shfl_xor(q0, 16); q0 += __shfl_xor(q0, 32);
    s1 += __shfl_xor(s1, 16); s1 += __shfl_xor(s1, 32);
    q1 += __shfl_xor(q1, 16); q1 += __shfl_xor(q1, 32);
    if (lane < 16) {
        atomicAdd(&lst[sl], s0);
        atomicAdd(&lst[32 + sl], q0);
    } else if (lane < 32) {
        atomicAdd(&lst[16 + sl], s1);
        atomicAdd(&lst[48 + sl], q1);
    }
    __syncthreads();
    if (tid < 64)
        atomicAdd(&spart[(blockIdx.x & (NCOPY - 1)) * 64 + tid], lst[tid]);
}

// BN+ReLU apply. Prolog finalizes stats from NCOPY partials. Optional bf16
// out and/or fp32 out (both original order).
template <bool WF32, bool WBF>
__global__ __launch_bounds__(256) void k_bn(
    const __bf16* __restrict__ src, const float* __restrict__ spart,
    const float* __restrict__ gamma, const float* __restrict__ beta,
    float inv_cnt, int nrows,
    __bf16* __restrict__ dstb, float* __restrict__ dstf) {
    __shared__ float ss[64];
    __shared__ float sc[32], sh[32];
    const int tid = threadIdx.x;
    if (tid < 64) {
        float a = 0.f;
#pragma unroll
        for (int i = 0; i < NCOPY; ++i) a += spart[i * 64 + tid];
        ss[tid] = a;
    }
    __syncthreads();
    if (tid < 32) {
        float mu = ss[tid] * inv_cnt;
        float var = ss[32 + tid] * inv_cnt - mu * mu;
        float s = gamma[tid] * rsqrtf(var + EPSV);
        sc[tid] = s;
        sh[tid] = beta[tid] - mu * s;
    }
    __syncthreads();
    const int gtid = blockIdx.x * blockDim.x + tid;
    const int c0 = (gtid & 3) * 8;
    float scale[8], shift[8];
#pragma unroll
    for (int i = 0; i < 8; ++i) { scale[i] = sc[c0 + i]; shift[i] = sh[c0 + i]; }
    const int rstride = (gridDim.x * blockDim.x) >> 2;
    for (int r = gtid >> 2; r < nrows; r += rstride) {
        const size_t off = (size_t)r * 32 + c0;
        bf16_8 v = *(const bf16_8*)(src + off);
        float y[8];
#pragma unroll
        for (int i = 0; i < 8; ++i) y[i] = fmaxf(fmaf((float)v[i], scale[i], shift[i]), 0.f);
        if (WBF) {
            bf16_8 o;
#pragma unroll
            for (int i = 0; i < 8; ++i) o[i] = (__bf16)y[i];
            *(bf16_8*)(dstb + off) = o;
        }
        if (WF32) {
            f32x4 lo, hi;
#pragma unroll
            for (int i = 0; i < 4; ++i) { lo[i] = y[i]; hi[i] = y[4 + i]; }
            *(f32x4*)(dstf + off) = lo;
            *(f32x4*)(dstf + off + 4) = hi;
        }
    }
}

extern "C" void kernel_launch(void* const* d_in, const int* in_sizes, int n_in,
                              void* d_out, int out_size, void* d_ws, size_t ws_size,
                              hipStream_t stream) {
    const float* feats = (const float*)d_in[0];
    const int* nbr     = (const int*)d_in[1];
    const int* child   = (const int*)d_in[2];
    const float* W1  = (const float*)d_in[3];
    const float* W2a = (const float*)d_in[4];
    const float* W2b = (const float*)d_in[5];
    const float* W3  = (const float*)d_in[6];
    const float* g1 = (const float*)d_in[7];  const float* b1 = (const float*)d_in[8];
    const float* g2 = (const float*)d_in[9];  const float* b2 = (const float*)d_in[10];
    const float* g3 = (const float*)d_in[11]; const float* b3 = (const float*)d_in[12];
    const float* g4 = (const float*)d_in[13]; const float* b4 = (const float*)d_in[14];

    const int N = in_sizes[0] / 3;          // 131072 (multiple of 64)
    const int M8 = in_sizes[2];
    const int M = M8 / 8;
    const int MP64 = ((M + 63) / 64) * 64;

    float* outp = (float*)d_out;               // [M,32]
    float* ft2p = outp + (size_t)M * 32;       // [N,32]

    char* ws = (char*)d_ws;
    float* statsAll = (float*)ws;                         // 4 x NCOPY x 64
    __bf16* w1t  = (__bf16*)(ws + 32768);                 // [27][32][32]
    __bf16* w2at = w1t + 27648;
    __bf16* w2bt = w2at + 27648;
    __bf16* w3t  = w2bt + 27648;                          // [8][32][32]
    __bf16* X  = (__bf16*)(ws + 215040);                  // [N+1,32]
    __bf16* T  = X + (size_t)(N + 1) * 32;
    __bf16* FB = T + (size_t)(N + 1) * 32;
    int* nbrT   = (int*)(FB + (size_t)(N + 1) * 32);      // [27][N]
    int* childT = nbrT + (size_t)27 * N;                  // [8][MP64]

    float* s1 = statsAll;
    float* s2 = statsAll + NCOPY * 64;
    float* s3 = statsAll + 2 * NCOPY * 64;
    float* s4 = statsAll + 3 * NCOPY * 64;

    const int ptot = N * 32 + 96 + 3 * 27648 + 8192 + 4 * NCOPY * 64;
    k_prep<<<(ptot + 255) / 256, 256, 0, stream>>>(
        feats, W1, W2a, W2b, W3, FB, X, T, w1t, w2at, w2bt, w3t, statsAll, N);
    k_tr<<<N / 64, 256, 0, stream>>>(nbr, nbrT, N);
    k_tr3<<<MP64 / 64, 256, 0, stream>>>(child, childT, M, MP64, N);

    const float invN = 1.f / N, invM = 1.f / M;

    // x1 = conv1(featsb)                     FB -> X, s1
    k_conv<27, false><<<N / 64, 256, 0, stream>>>(FB, nbrT, w1t, nullptr, X, s1, N, N);
    // t1 = bnrelu1(x1)                       X -> T
    k_bn<false, true><<<1024, 256, 0, stream>>>(X, s1, g1, b1, invN, N, T, nullptr);
    // br1 = conv2a(t1)                       T -> FB, s2
    k_conv<27, false><<<N / 64, 256, 0, stream>>>(T, nbrT, w2at, nullptr, FB, s2, N, N);
    // t2 = bnrelu2(br1)                      FB -> T
    k_bn<false, true><<<1024, 256, 0, stream>>>(FB, s2, g2, b2, invN, N, T, nullptr);
    // s = x1 + conv2b(t2)                    T (+X) -> FB, s3
    k_conv<27, true><<<N / 64, 256, 0, stream>>>(T, nbrT, w2bt, X, FB, s3, N, N);
    // ft2 = bnrelu3(s)                       FB -> T (bf16) + ft2p (fp32)
    k_bn<true, true><<<1024, 256, 0, stream>>>(FB, s3, g3, b3, invN, N, T, ft2p);
    // x3 = conv3(ft2)                        T -> X rows [0,M), s4
    k_conv<8, false><<<MP64 / 64, 256, 0, stream>>>(T, childT, w3t, nullptr, X, s4, M, MP64);
    // out = bnrelu4(x3)                      X -> outp
    k_bn<true, false><<<1024, 256, 0, stream>>>(X, s4, g4, b4, invM, M, nullptr, outp);
}